// Round 1
// baseline (974.475 us; speedup 1.0000x reference)
//
#include <hip/hip_runtime.h>

#define D 64
#define NNODES 545
#define SNAPN 544   // max t+c

// ---------------- init: copy x -> H (d_out), transpose weights into ws ----------------
// wT layout (12 mats of 64x64, [e][d]): 0 taL,1 taR,2 caL,3 caR,4 tbL,5 tbR,6 cbL,7 cbR,8 uL,9 uR,10 oL,11 oR
__global__ void k_init(const float* __restrict__ x,
                       const float* __restrict__ w_ta, const float* __restrict__ w_ca,
                       const float* __restrict__ w_tb, const float* __restrict__ w_cb,
                       const float* __restrict__ w_u,  const float* __restrict__ w_o,
                       float* __restrict__ H, float* __restrict__ wT)
{
    int idx = blockIdx.x * 256 + threadIdx.x;
    const int NH = 2 * NNODES * D;  // 69760
    if (idx < NH) { H[idx] = x[idx]; return; }
    int j = idx - NH;
    if (j >= 12 * 4096) return;
    int mat = j >> 12;
    int r   = j & 4095;
    int e   = r >> 6;
    int dd  = r & 63;
    const float* src;
    switch (mat >> 1) {
        case 0: src = w_ta; break;
        case 1: src = w_ca; break;
        case 2: src = w_tb; break;
        case 3: src = w_cb; break;
        case 4: src = w_u;  break;
        default: src = w_o; break;
    }
    int half = mat & 1;
    wT[j] = src[dd * 128 + half * 64 + e];
}

// ---------------- kernel A: per-segment staging ----------------
// Computes, per (batch, node-tile of 4):
//   Pb[gn][d]  = (w_{t|c}b[:, :64] @ h_block)[d]         (raw, no bias/Q)
//   snap[gn][d]= h[node][d]  (snapshot so kernel B never reads H)
//   per-tile softmax stats of Pa = (w_{t|c}a[:, :64] @ h_block): max, sumexp, sumexp*Nb
__global__ void k_stage(const float* __restrict__ H,
                        const float* __restrict__ wT,
                        float* __restrict__ snap,   // [2][544][64]
                        float* __restrict__ Pb,     // [2][544][64]
                        float* __restrict__ stT,    // [2][3][128][64]
                        float* __restrict__ stC,    // [2][3][128][64]
                        int off, int t, int c)
{
    __shared__ float Hs[4][64];
    __shared__ float PaS[4][64];
    int b = blockIdx.y;
    int tilesT = (t + 3) >> 2;
    int tile = blockIdx.x;
    int ln = threadIdx.x >> 6;
    int d  = threadIdx.x & 63;
    int regionC = (tile >= tilesT) ? 1 : 0;
    int tl = regionC ? (tile - tilesT) : tile;
    int n0 = tl * 4;
    int cnt = regionC ? c : t;
    int nodeBase = off + (regionC ? t : 0);
    int valid = (n0 + ln) < cnt;
    const float* Hb = H + b * NNODES * D;

    Hs[ln][d] = valid ? Hb[(nodeBase + n0 + ln) * D + d] : 0.0f;
    __syncthreads();

    const float* wA = wT + (regionC ? 2 * 4096 : 0);        // caL : taL
    const float* wB = wT + (regionC ? 6 * 4096 : 4 * 4096); // cbL : tbL
    float acc_a = 0.0f, acc_b = 0.0f;
#pragma unroll 8
    for (int e = 0; e < 64; e++) {
        float h = Hs[ln][e];
        acc_a = fmaf(wA[e * 64 + d], h, acc_a);
        acc_b = fmaf(wB[e * 64 + d], h, acc_b);
    }
    int gn = (regionC ? t : 0) + n0 + ln;
    float* snapB = snap + b * SNAPN * D;
    float* PbB   = Pb   + b * SNAPN * D;
    if (valid) {
        PbB[gn * D + d]   = acc_b;
        snapB[gn * D + d] = Hs[ln][d];
    }
    PaS[ln][d] = valid ? acc_a : -3.0e38f;
    __syncthreads();

    if (threadIdx.x < 64) {
        int dd = threadIdx.x;
        float mx = -3.0e38f;
#pragma unroll
        for (int l = 0; l < 4; l++) mx = fmaxf(mx, PaS[l][dd]);
        int lim = cnt - n0; if (lim > 4) lim = 4;
        float se = 0.0f, sw = 0.0f;
        for (int l = 0; l < lim; l++) {
            float ev = expf(PaS[l][dd] - mx);
            se += ev;
            sw += ev * Hs[l][dd];
        }
        float* st = (regionC ? stC : stT) + b * 3 * 128 * 64;
        st[0 * 8192 + tl * 64 + dd] = mx;
        st[1 * 8192 + tl * 64 + dd] = se;
        st[2 * 8192 + tl * 64 + dd] = sw;
    }
}

// ---------------- kernel B: per-(k,d) gate compute + update ----------------
__global__ void k_gate(float* __restrict__ H,
                       const float* __restrict__ wT,
                       const float* __restrict__ snap,
                       const float* __restrict__ Pb,
                       const float* __restrict__ stT,
                       const float* __restrict__ stC,
                       const float* __restrict__ b_ta, const float* __restrict__ b_ca,
                       const float* __restrict__ b_tb, const float* __restrict__ b_cb,
                       const float* __restrict__ w_mix,
                       const float* __restrict__ b_u, const float* __restrict__ b_o,
                       float* __restrict__ updWS,
                       int off, int t, int c, int storeUpd, int reapply, int prev_i)
{
    __shared__ float mS[4][64];
    __shared__ float sS[4][64];
    int b  = blockIdx.y;
    int kl = threadIdx.x >> 6;
    int d  = threadIdx.x & 63;
    int k  = blockIdx.x * 4 + kl;
    int valid = (k < c) ? 1 : 0;
    int i = off + t;
    const float* snapB = snap + b * SNAPN * D;
    const float* PbB   = Pb   + b * SNAPN * D;

    // ---- combine per-tile softmax stats for this d ----
    int nT = (t + 3) >> 2, nC = (c + 3) >> 2;
    const float* sT = stT + b * 3 * 8192;
    float mT = -3.0e38f, seT = 0.0f, swT = 0.0f;
    for (int tl = 0; tl < nT; tl++) {
        float m1 = sT[tl * 64 + d];
        float s1 = sT[8192 + tl * 64 + d];
        float w1 = sT[2 * 8192 + tl * 64 + d];
        float nm = fmaxf(mT, m1);
        float f0 = expf(mT - nm), f1 = expf(m1 - nm);
        seT = seT * f0 + s1 * f1;
        swT = swT * f0 + w1 * f1;
        mT = nm;
    }
    const float* sC = stC + b * 3 * 8192;
    float mC = -3.0e38f, seC = 0.0f, swC = 0.0f;
    for (int tl = 0; tl < nC; tl++) {
        float m1 = sC[tl * 64 + d];
        float s1 = sC[8192 + tl * 64 + d];
        float w1 = sC[2 * 8192 + tl * 64 + d];
        float nm = fmaxf(mC, m1);
        float f0 = expf(mC - nm), f1 = expf(m1 - nm);
        seC = seC * f0 + s1 * f1;
        swC = swC * f0 + w1 * f1;
        mC = nm;
    }

    // ---- Q offsets (per (k,d)): Q[d,k] = w[:,64:] @ C, plus bias ----
    float offTa = b_ta[d], offCa = b_ca[d], offTb = b_tb[d], offCb = b_cb[d];
    const float* taR = wT + 1 * 4096;
    const float* caR = wT + 3 * 4096;
    const float* tbR = wT + 5 * 4096;
    const float* cbR = wT + 7 * 4096;
    int kk = valid ? k : 0;
    const float* cptr = snapB + (t + kk) * 64;
#pragma unroll 4
    for (int e = 0; e < 64; e++) {
        float cv = cptr[e];
        offTa = fmaf(taR[e * 64 + d], cv, offTa);
        offCa = fmaf(caR[e * 64 + d], cv, offCa);
        offTb = fmaf(tbR[e * 64 + d], cv, offTb);
        offCb = fmaf(cbR[e * 64 + d], cv, offCb);
    }

    // ---- A part (softmax * w_mix, factorized, O(1)) ----
    float aT = mT + offTa, aC = mC + offCa;
    float M  = fmaxf(aT, aC);
    float eT = expf(aT - M), eC = expf(aC - M);
    float denom = eT * seT + eC * seC;
    float Apart = w_mix[d] * (eT * swT + eC * swC) / denom;

    // ---- B part: sum_n f(Pb[n,d]+off) * Nb[d,n], f(x)=x/(1+|x|) ----
    float acc = 0.0f;
    for (int n = 0; n < t; n++) {
        float p = PbB[n * 64 + d] + offTb;
        float f = p / (1.0f + fabsf(p));
        acc = fmaf(f, snapB[n * 64 + d], acc);
    }
    for (int n = t; n < t + c; n++) {
        float p = PbB[n * 64 + d] + offCb;
        float f = p / (1.0f + fabsf(p));
        acc = fmaf(f, snapB[n * 64 + d], acc);
    }
    float mval = Apart + acc;

    mS[kl][d] = mval;
    sS[kl][d] = snapB[(t + kk) * 64 + d];
    __syncthreads();

    // ---- phase 4: u, o, update ----
    const float* uL = wT + 8 * 4096;
    const float* uR = wT + 9 * 4096;
    const float* oL = wT + 10 * 4096;
    const float* oR = wT + 11 * 4096;
    float zU = b_u[d], zO = b_o[d];
#pragma unroll 4
    for (int e = 0; e < 64; e++) {
        float mv = mS[kl][e], sv = sS[kl][e];
        zU = fmaf(mv, uL[e * 64 + d], zU);
        zU = fmaf(sv, uR[e * 64 + d], zU);
        zO = fmaf(mv, oL[e * 64 + d], zO);
        zO = fmaf(sv, oR[e * 64 + d], zO);
    }
    float u  = 1.0f / (1.0f + expf(-zU));
    float o  = fmaxf(zO, 0.0f);
    float mm = mS[kl][d];
    float sv = sS[kl][d];
    float upd = u * o + (1.0f - u) * mm - sv;

    float* Hb = H + b * NNODES * D;
    if (valid) {
        Hb[(i + k) * D + d] += upd;
        if (storeUpd) updWS[b * 2048 + k * 64 + d] = upd;
    }
    // replicate reference quirk: seg-2 of each prop re-applies seg-1's update
    if (reapply && blockIdx.x == 0) {
#pragma unroll
        for (int r = 0; r < 8; r++) {
            int idx = threadIdx.x + 256 * r;  // 2048 = 32 nodes * 64
            Hb[(prev_i + (idx >> 6)) * D + (idx & 63)] += updWS[b * 2048 + idx];
        }
    }
}

extern "C" void kernel_launch(void* const* d_in, const int* in_sizes, int n_in,
                              void* d_out, int out_size, void* d_ws, size_t ws_size,
                              hipStream_t stream) {
    const float* x    = (const float*)d_in[0];
    // d_in[1] = edge_index (unused by reference math)
    const float* w_ta = (const float*)d_in[2];
    const float* b_ta = (const float*)d_in[3];
    const float* w_ca = (const float*)d_in[4];
    const float* b_ca = (const float*)d_in[5];
    const float* w_tb = (const float*)d_in[6];
    const float* b_tb = (const float*)d_in[7];
    const float* w_cb = (const float*)d_in[8];
    const float* b_cb = (const float*)d_in[9];
    const float* w_mix= (const float*)d_in[10];
    const float* w_u  = (const float*)d_in[11];
    const float* b_u  = (const float*)d_in[12];
    const float* w_o  = (const float*)d_in[13];
    const float* b_o  = (const float*)d_in[14];

    float* H  = (float*)d_out;           // evolving state, [2][545][64] (= output layout)
    float* ws = (float*)d_ws;
    float* wT   = ws;                    // 12*4096 = 49152
    float* snap = wT + 49152;            // 2*544*64 = 69632
    float* Pb   = snap + 69632;          // 69632
    float* stT  = Pb + 69632;            // 2*3*128*64 = 49152
    float* stC  = stT + 49152;           // 49152
    float* upd  = stC + 49152;           // 2*2048 = 4096   (total ~1.11 MB)

    {
        int total = 2 * NNODES * D + 12 * 4096;
        k_init<<<dim3((total + 255) / 256), 256, 0, stream>>>(
            x, w_ta, w_ca, w_tb, w_cb, w_u, w_o, H, wT);
    }

    struct St { int off, t, c, store, reapply, prev_i; };
    const St steps[4] = {
        {0,   1,  32, 1, 0, 0},    // fwd seg1
        {1,  32, 512, 0, 1, 1},    // fwd seg2 (re-applies seg1 upd at cols 1..32)
        {0, 512,  32, 1, 0, 0},    // rev seg1
        {512, 32,  1, 0, 1, 512},  // rev seg2 (re-applies seg1 upd at cols 512..543)
    };
    for (int p = 0; p < 2; p++) {
        for (int s = 0; s < 4; s++) {
            St st = steps[s];
            int tilesT = (st.t + 3) / 4, tilesC = (st.c + 3) / 4;
            k_stage<<<dim3(tilesT + tilesC, 2), 256, 0, stream>>>(
                H, wT, snap, Pb, stT, stC, st.off, st.t, st.c);
            k_gate<<<dim3((st.c + 3) / 4, 2), 256, 0, stream>>>(
                H, wT, snap, Pb, stT, stC,
                b_ta, b_ca, b_tb, b_cb, w_mix, b_u, b_o, upd,
                st.off, st.t, st.c, st.store, st.reapply, st.prev_i);
        }
    }
}

// Round 4
// 457.280 us; speedup vs baseline: 2.1310x; 2.1310x over previous
//
#include <hip/hip_runtime.h>

#define D 64
#define NNODES 545
#define SNAPN 544   // max t+c
#define CN 64       // n-chunk rows staged in LDS

// ---------------- init: copy x -> H (d_out), transpose weights into ws ----------------
// wT layout (12 mats of 64x64, [e][d]): 0 taL,1 taR,2 caL,3 caR,4 tbL,5 tbR,6 cbL,7 cbR,8 uL,9 uR,10 oL,11 oR
__global__ void k_init(const float* __restrict__ x,
                       const float* __restrict__ w_ta, const float* __restrict__ w_ca,
                       const float* __restrict__ w_tb, const float* __restrict__ w_cb,
                       const float* __restrict__ w_u,  const float* __restrict__ w_o,
                       float* __restrict__ H, float* __restrict__ wT)
{
    int idx = blockIdx.x * 256 + threadIdx.x;
    const int NH = 2 * NNODES * D;  // 69760
    if (idx < NH) { H[idx] = x[idx]; return; }
    int j = idx - NH;
    if (j >= 12 * 4096) return;
    int mat = j >> 12;
    int r   = j & 4095;
    int e   = r >> 6;
    int dd  = r & 63;
    const float* src;
    switch (mat >> 1) {
        case 0: src = w_ta; break;
        case 1: src = w_ca; break;
        case 2: src = w_tb; break;
        case 3: src = w_cb; break;
        case 4: src = w_u;  break;
        default: src = w_o; break;
    }
    int half = mat & 1;
    wT[j] = src[dd * 128 + half * 64 + e];
}

// ---------------- kernel A: per-segment staging (identical to round-1 passing version) ----
__global__ void k_stage(const float* __restrict__ H,
                        const float* __restrict__ wT,
                        float* __restrict__ snap,   // [2][544][64]
                        float* __restrict__ Pb,     // [2][544][64]
                        float* __restrict__ stT,    // [2][3][128][64]
                        float* __restrict__ stC,    // [2][3][128][64]
                        int off, int t, int c)
{
    __shared__ float Hs[4][64];
    __shared__ float PaS[4][64];
    int b = blockIdx.y;
    int tilesT = (t + 3) >> 2;
    int tile = blockIdx.x;
    int ln = threadIdx.x >> 6;
    int d  = threadIdx.x & 63;
    int regionC = (tile >= tilesT) ? 1 : 0;
    int tl = regionC ? (tile - tilesT) : tile;
    int n0 = tl * 4;
    int cnt = regionC ? c : t;
    int nodeBase = off + (regionC ? t : 0);
    int valid = (n0 + ln) < cnt;
    const float* Hb = H + b * NNODES * D;

    Hs[ln][d] = valid ? Hb[(nodeBase + n0 + ln) * D + d] : 0.0f;
    __syncthreads();

    const float* wA = wT + (regionC ? 2 * 4096 : 0);        // caL : taL
    const float* wB = wT + (regionC ? 6 * 4096 : 4 * 4096); // cbL : tbL
    float acc_a = 0.0f, acc_b = 0.0f;
#pragma unroll 8
    for (int e = 0; e < 64; e++) {
        float h = Hs[ln][e];
        acc_a = fmaf(wA[e * 64 + d], h, acc_a);
        acc_b = fmaf(wB[e * 64 + d], h, acc_b);
    }
    int gn = (regionC ? t : 0) + n0 + ln;
    float* snapB = snap + b * SNAPN * D;
    float* PbB   = Pb   + b * SNAPN * D;
    if (valid) {
        PbB[gn * D + d]   = acc_b;
        snapB[gn * D + d] = Hs[ln][d];
    }
    PaS[ln][d] = valid ? acc_a : -3.0e38f;
    __syncthreads();

    if (threadIdx.x < 64) {
        int dd = threadIdx.x;
        float mx = -3.0e38f;
#pragma unroll
        for (int l = 0; l < 4; l++) mx = fmaxf(mx, PaS[l][dd]);
        int lim = cnt - n0; if (lim > 4) lim = 4;
        float se = 0.0f, sw = 0.0f;
        for (int l = 0; l < lim; l++) {
            float ev = expf(PaS[l][dd] - mx);
            se += ev;
            sw += ev * Hs[l][dd];
        }
        float* st = (regionC ? stC : stT) + b * 3 * 128 * 64;
        st[0 * 8192 + tl * 64 + dd] = mx;
        st[1 * 8192 + tl * 64 + dd] = se;
        st[2 * 8192 + tl * 64 + dd] = sw;
    }
}

// ---------------- kernel B: round-1 structure; ONLY phase C changed to LDS-chunked ------
__global__ void k_gate(float* __restrict__ H,
                       const float* __restrict__ wT,
                       const float* __restrict__ snap,
                       const float* __restrict__ Pb,
                       const float* __restrict__ stT,
                       const float* __restrict__ stC,
                       const float* __restrict__ b_ta, const float* __restrict__ b_ca,
                       const float* __restrict__ b_tb, const float* __restrict__ b_cb,
                       const float* __restrict__ w_mix,
                       const float* __restrict__ b_u, const float* __restrict__ b_o,
                       float* __restrict__ updWS,
                       int off, int t, int c, int storeUpd, int reapply, int prev_i)
{
    __shared__ float PS[CN][D];   // 16KB Pb chunk
    __shared__ float SS[CN][D];   // 16KB snap chunk
    __shared__ float mS[4][64];
    __shared__ float sS[4][64];
    int b  = blockIdx.y;
    int kl = threadIdx.x >> 6;
    int d  = threadIdx.x & 63;
    int k  = blockIdx.x * 4 + kl;
    int valid = (k < c) ? 1 : 0;
    int i = off + t;
    const float* snapB = snap + b * SNAPN * D;
    const float* PbB   = Pb   + b * SNAPN * D;

    // ---- sequential softmax-stat merge (exact round-1 code) ----
    int nT = (t + 3) >> 2, nC = (c + 3) >> 2;
    const float* sT = stT + b * 3 * 8192;
    float mT = -3.0e38f, seT = 0.0f, swT = 0.0f;
    for (int tl = 0; tl < nT; tl++) {
        float m1 = sT[tl * 64 + d];
        float s1 = sT[8192 + tl * 64 + d];
        float w1 = sT[2 * 8192 + tl * 64 + d];
        float nm = fmaxf(mT, m1);
        float f0 = expf(mT - nm), f1 = expf(m1 - nm);
        seT = seT * f0 + s1 * f1;
        swT = swT * f0 + w1 * f1;
        mT = nm;
    }
    const float* sC = stC + b * 3 * 8192;
    float mC = -3.0e38f, seC = 0.0f, swC = 0.0f;
    for (int tl = 0; tl < nC; tl++) {
        float m1 = sC[tl * 64 + d];
        float s1 = sC[8192 + tl * 64 + d];
        float w1 = sC[2 * 8192 + tl * 64 + d];
        float nm = fmaxf(mC, m1);
        float f0 = expf(mC - nm), f1 = expf(m1 - nm);
        seC = seC * f0 + s1 * f1;
        swC = swC * f0 + w1 * f1;
        mC = nm;
    }

    // ---- Q offsets (exact round-1 code) ----
    float offTa = b_ta[d], offCa = b_ca[d], offTb = b_tb[d], offCb = b_cb[d];
    const float* taR = wT + 1 * 4096;
    const float* caR = wT + 3 * 4096;
    const float* tbR = wT + 5 * 4096;
    const float* cbR = wT + 7 * 4096;
    int kk = valid ? k : 0;
    const float* cptr = snapB + (t + kk) * 64;
#pragma unroll 4
    for (int e = 0; e < 64; e++) {
        float cv = cptr[e];
        offTa = fmaf(taR[e * 64 + d], cv, offTa);
        offCa = fmaf(caR[e * 64 + d], cv, offCa);
        offTb = fmaf(tbR[e * 64 + d], cv, offTb);
        offCb = fmaf(cbR[e * 64 + d], cv, offCb);
    }

    // ---- A part (exact round-1 code) ----
    float aT = mT + offTa, aC = mC + offCa;
    float M  = fmaxf(aT, aC);
    float eT = expf(aT - M), eC = expf(aC - M);
    float denom = eT * seT + eC * seC;
    float Apart = w_mix[d] * (eT * swT + eC * swC) / denom;

    // ---- B part: same math & accumulation order as round 1, but data staged via LDS ----
    float acc = 0.0f;
    int NTOT = t + c;
    for (int n0 = 0; n0 < NTOT; n0 += CN) {
        int cnt = NTOT - n0; if (cnt > CN) cnt = CN;
        __syncthreads();   // protect previous chunk's reads before overwrite
        int tot4 = cnt * (D / 4);
        const float4* gp = (const float4*)(PbB   + n0 * D);
        const float4* gs = (const float4*)(snapB + n0 * D);
        float4* lp = (float4*)&PS[0][0];
        float4* ls = (float4*)&SS[0][0];
        for (int idx4 = threadIdx.x; idx4 < tot4; idx4 += 256) {
            lp[idx4] = gp[idx4];
            ls[idx4] = gs[idx4];
        }
        __syncthreads();
        for (int n = 0; n < cnt; n++) {
            int gn = n0 + n;
            float p = PS[n][d] + ((gn < t) ? offTb : offCb);
            float f = p / (1.0f + fabsf(p));
            acc = fmaf(f, SS[n][d], acc);
        }
    }
    float mval = Apart + acc;

    mS[kl][d] = mval;
    sS[kl][d] = snapB[(t + kk) * 64 + d];
    __syncthreads();

    // ---- u, o, update (exact round-1 code) ----
    const float* uL = wT + 8 * 4096;
    const float* uR = wT + 9 * 4096;
    const float* oL = wT + 10 * 4096;
    const float* oR = wT + 11 * 4096;
    float zU = b_u[d], zO = b_o[d];
#pragma unroll 4
    for (int e = 0; e < 64; e++) {
        float mv = mS[kl][e], sv = sS[kl][e];
        zU = fmaf(mv, uL[e * 64 + d], zU);
        zU = fmaf(sv, uR[e * 64 + d], zU);
        zO = fmaf(mv, oL[e * 64 + d], zO);
        zO = fmaf(sv, oR[e * 64 + d], zO);
    }
    float u  = 1.0f / (1.0f + expf(-zU));
    float o  = fmaxf(zO, 0.0f);
    float mm = mS[kl][d];
    float sv = sS[kl][d];
    float upd = u * o + (1.0f - u) * mm - sv;

    float* Hb = H + b * NNODES * D;
    if (valid) {
        Hb[(i + k) * D + d] += upd;
        if (storeUpd) updWS[b * 2048 + k * 64 + d] = upd;
    }
    // replicate reference quirk: seg-2 of each prop re-applies seg-1's update
    if (reapply && blockIdx.x == 0) {
#pragma unroll
        for (int r = 0; r < 8; r++) {
            int idx = threadIdx.x + 256 * r;  // 2048 = 32 nodes * 64
            Hb[(prev_i + (idx >> 6)) * D + (idx & 63)] += updWS[b * 2048 + idx];
        }
    }
}

extern "C" void kernel_launch(void* const* d_in, const int* in_sizes, int n_in,
                              void* d_out, int out_size, void* d_ws, size_t ws_size,
                              hipStream_t stream) {
    const float* x    = (const float*)d_in[0];
    const float* w_ta = (const float*)d_in[2];
    const float* b_ta = (const float*)d_in[3];
    const float* w_ca = (const float*)d_in[4];
    const float* b_ca = (const float*)d_in[5];
    const float* w_tb = (const float*)d_in[6];
    const float* b_tb = (const float*)d_in[7];
    const float* w_cb = (const float*)d_in[8];
    const float* b_cb = (const float*)d_in[9];
    const float* w_mix= (const float*)d_in[10];
    const float* w_u  = (const float*)d_in[11];
    const float* b_u  = (const float*)d_in[12];
    const float* w_o  = (const float*)d_in[13];
    const float* b_o  = (const float*)d_in[14];

    float* H  = (float*)d_out;           // evolving state, [2][545][64]
    float* ws = (float*)d_ws;
    float* wT   = ws;                    // 12*4096 = 49152
    float* snap = wT + 49152;            // 2*544*64 = 69632
    float* Pb   = snap + 69632;          // 69632
    float* stT  = Pb + 69632;            // 2*3*128*64 = 49152
    float* stC  = stT + 49152;           // 49152
    float* upd  = stC + 49152;           // 2*2048 = 4096

    {
        int total = 2 * NNODES * D + 12 * 4096;
        k_init<<<dim3((total + 255) / 256), 256, 0, stream>>>(
            x, w_ta, w_ca, w_tb, w_cb, w_u, w_o, H, wT);
    }

    struct St { int off, t, c, store, reapply, prev_i; };
    const St steps[4] = {
        {0,   1,  32, 1, 0, 0},
        {1,  32, 512, 0, 1, 1},
        {0, 512,  32, 1, 0, 0},
        {512, 32,  1, 0, 1, 512},
    };
    for (int p = 0; p < 2; p++) {
        for (int s = 0; s < 4; s++) {
            St st = steps[s];
            int tilesT = (st.t + 3) / 4, tilesC = (st.c + 3) / 4;
            k_stage<<<dim3(tilesT + tilesC, 2), 256, 0, stream>>>(
                H, wT, snap, Pb, stT, stC, st.off, st.t, st.c);
            k_gate<<<dim3((st.c + 3) / 4, 2), 256, 0, stream>>>(
                H, wT, snap, Pb, stT, stC,
                b_ta, b_ca, b_tb, b_cb, w_mix, b_u, b_o, upd,
                st.off, st.t, st.c, st.store, st.reapply, st.prev_i);
        }
    }
}

// Round 7
// 426.948 us; speedup vs baseline: 2.2824x; 1.0710x over previous
//
#include <hip/hip_runtime.h>

#define D 64
#define NNODES 545
#define SNAPN 544   // max t+c
#define CN 64       // n-chunk rows staged in LDS

// ---------------- init: copy x -> H (d_out), transpose weights into ws ----------------
// wT layout (12 mats of 64x64, [e][d]): 0 taL,1 taR,2 caL,3 caR,4 tbL,5 tbR,6 cbL,7 cbR,8 uL,9 uR,10 oL,11 oR
__global__ void k_init(const float* __restrict__ x,
                       const float* __restrict__ w_ta, const float* __restrict__ w_ca,
                       const float* __restrict__ w_tb, const float* __restrict__ w_cb,
                       const float* __restrict__ w_u,  const float* __restrict__ w_o,
                       float* __restrict__ H, float* __restrict__ wT)
{
    int idx = blockIdx.x * 256 + threadIdx.x;
    const int NH = 2 * NNODES * D;  // 69760
    if (idx < NH) { H[idx] = x[idx]; return; }
    int j = idx - NH;
    if (j >= 12 * 4096) return;
    int mat = j >> 12;
    int r   = j & 4095;
    int e   = r >> 6;
    int dd  = r & 63;
    const float* src;
    switch (mat >> 1) {
        case 0: src = w_ta; break;
        case 1: src = w_ca; break;
        case 2: src = w_tb; break;
        case 3: src = w_cb; break;
        case 4: src = w_u;  break;
        default: src = w_o; break;
    }
    int half = mat & 1;
    wT[j] = src[dd * 128 + half * 64 + e];
}

// ---------------- kernel A: per-segment staging (verified round-1/4 version) ----------
__global__ void k_stage(const float* __restrict__ H,
                        const float* __restrict__ wT,
                        float* __restrict__ snap,   // [2][544][64]
                        float* __restrict__ Pb,     // [2][544][64]
                        float* __restrict__ stT,    // [2][3][128][64]
                        float* __restrict__ stC,    // [2][3][128][64]
                        int off, int t, int c)
{
    __shared__ float Hs[4][64];
    __shared__ float PaS[4][64];
    int b = blockIdx.y;
    int tilesT = (t + 3) >> 2;
    int tile = blockIdx.x;
    int ln = threadIdx.x >> 6;
    int d  = threadIdx.x & 63;
    int regionC = (tile >= tilesT) ? 1 : 0;
    int tl = regionC ? (tile - tilesT) : tile;
    int n0 = tl * 4;
    int cnt = regionC ? c : t;
    int nodeBase = off + (regionC ? t : 0);
    int valid = (n0 + ln) < cnt;
    const float* Hb = H + b * NNODES * D;

    Hs[ln][d] = valid ? Hb[(nodeBase + n0 + ln) * D + d] : 0.0f;
    __syncthreads();

    const float* wA = wT + (regionC ? 2 * 4096 : 0);        // caL : taL
    const float* wB = wT + (regionC ? 6 * 4096 : 4 * 4096); // cbL : tbL
    float acc_a = 0.0f, acc_b = 0.0f;
#pragma unroll 8
    for (int e = 0; e < 64; e++) {
        float h = Hs[ln][e];
        acc_a = fmaf(wA[e * 64 + d], h, acc_a);
        acc_b = fmaf(wB[e * 64 + d], h, acc_b);
    }
    int gn = (regionC ? t : 0) + n0 + ln;
    float* snapB = snap + b * SNAPN * D;
    float* PbB   = Pb   + b * SNAPN * D;
    if (valid) {
        PbB[gn * D + d]   = acc_b;
        snapB[gn * D + d] = Hs[ln][d];
    }
    PaS[ln][d] = valid ? acc_a : -3.0e38f;
    __syncthreads();

    if (threadIdx.x < 64) {
        int dd = threadIdx.x;
        float mx = -3.0e38f;
#pragma unroll
        for (int l = 0; l < 4; l++) mx = fmaxf(mx, PaS[l][dd]);
        int lim = cnt - n0; if (lim > 4) lim = 4;
        float se = 0.0f, sw = 0.0f;
        for (int l = 0; l < lim; l++) {
            float ev = expf(PaS[l][dd] - mx);
            se += ev;
            sw += ev * Hs[l][dd];
        }
        float* st = (regionC ? stC : stT) + b * 3 * 128 * 64;
        st[0 * 8192 + tl * 64 + dd] = mx;
        st[1 * 8192 + tl * 64 + dd] = se;
        st[2 * 8192 + tl * 64 + dd] = sw;
    }
}

// ---------------- k_merge: per-(b,region,d) sequential stats merge ----------------
// Body is the round-4 k_gate merge loop, verbatim (run once instead of per-block).
// stFin layout: [b][region][3][64] -> ((b*2+r)*3+s)*64+d
__global__ void k_merge(const float* __restrict__ stT,
                        const float* __restrict__ stC,
                        float* __restrict__ stFin,
                        int t, int c)
{
    int r = blockIdx.x;   // 0 = T region, 1 = C region
    int b = blockIdx.y;
    int d = threadIdx.x;  // 64 threads
    const float* st = (r ? stC : stT) + b * 3 * 8192;
    int cnt = r ? c : t;
    int ntl = (cnt + 3) >> 2;
    float m = -3.0e38f, se = 0.0f, sw = 0.0f;
    for (int tl = 0; tl < ntl; tl++) {
        float m1 = st[tl * 64 + d];
        float s1 = st[8192 + tl * 64 + d];
        float w1 = st[2 * 8192 + tl * 64 + d];
        float nm = fmaxf(m, m1);
        float f0 = expf(m - nm), f1 = expf(m1 - nm);
        se = se * f0 + s1 * f1;
        sw = sw * f0 + w1 * f1;
        m  = nm;
    }
    float* o = stFin + (b * 2 + r) * 192;
    o[d] = m; o[64 + d] = se; o[128 + d] = sw;
}

// ---------------- kernel B: round-4 verified structure; merge loops -> 6 loads -------
__global__ void k_gate(float* __restrict__ H,
                       const float* __restrict__ wT,
                       const float* __restrict__ snap,
                       const float* __restrict__ Pb,
                       const float* __restrict__ stFin,
                       const float* __restrict__ b_ta, const float* __restrict__ b_ca,
                       const float* __restrict__ b_tb, const float* __restrict__ b_cb,
                       const float* __restrict__ w_mix,
                       const float* __restrict__ b_u, const float* __restrict__ b_o,
                       float* __restrict__ updWS,
                       int off, int t, int c, int storeUpd, int reapply, int prev_i)
{
    __shared__ float PS[CN][D];   // 16KB Pb chunk
    __shared__ float SS[CN][D];   // 16KB snap chunk
    __shared__ float mS[4][64];
    __shared__ float sS[4][64];
    int b  = blockIdx.y;
    int kl = threadIdx.x >> 6;
    int d  = threadIdx.x & 63;
    int k  = blockIdx.x * 4 + kl;
    int valid = (k < c) ? 1 : 0;
    int i = off + t;
    const float* snapB = snap + b * SNAPN * D;
    const float* PbB   = Pb   + b * SNAPN * D;

    // ---- merged softmax stats (precomputed by k_merge) ----
    const float* fB = stFin + b * 384;
    float mT = fB[d],       seT = fB[64 + d],  swT = fB[128 + d];
    float mC = fB[192 + d], seC = fB[256 + d], swC = fB[320 + d];

    // ---- Q offsets (exact round-1/4 code) ----
    float offTa = b_ta[d], offCa = b_ca[d], offTb = b_tb[d], offCb = b_cb[d];
    const float* taR = wT + 1 * 4096;
    const float* caR = wT + 3 * 4096;
    const float* tbR = wT + 5 * 4096;
    const float* cbR = wT + 7 * 4096;
    int kk = valid ? k : 0;
    const float* cptr = snapB + (t + kk) * 64;
#pragma unroll 4
    for (int e = 0; e < 64; e++) {
        float cv = cptr[e];
        offTa = fmaf(taR[e * 64 + d], cv, offTa);
        offCa = fmaf(caR[e * 64 + d], cv, offCa);
        offTb = fmaf(tbR[e * 64 + d], cv, offTb);
        offCb = fmaf(cbR[e * 64 + d], cv, offCb);
    }

    // ---- A part (exact round-1/4 code) ----
    float aT = mT + offTa, aC = mC + offCa;
    float M  = fmaxf(aT, aC);
    float eT = expf(aT - M), eC = expf(aC - M);
    float denom = eT * seT + eC * seC;
    float Apart = w_mix[d] * (eT * swT + eC * swC) / denom;

    // ---- B part: LDS-chunked (exact round-4 code) ----
    float acc = 0.0f;
    int NTOT = t + c;
    for (int n0 = 0; n0 < NTOT; n0 += CN) {
        int cnt = NTOT - n0; if (cnt > CN) cnt = CN;
        __syncthreads();   // protect previous chunk's reads before overwrite
        int tot4 = cnt * (D / 4);
        const float4* gp = (const float4*)(PbB   + n0 * D);
        const float4* gs = (const float4*)(snapB + n0 * D);
        float4* lp = (float4*)&PS[0][0];
        float4* ls = (float4*)&SS[0][0];
        for (int idx4 = threadIdx.x; idx4 < tot4; idx4 += 256) {
            lp[idx4] = gp[idx4];
            ls[idx4] = gs[idx4];
        }
        __syncthreads();
        for (int n = 0; n < cnt; n++) {
            int gn = n0 + n;
            float p = PS[n][d] + ((gn < t) ? offTb : offCb);
            float f = p / (1.0f + fabsf(p));
            acc = fmaf(f, SS[n][d], acc);
        }
    }
    float mval = Apart + acc;

    mS[kl][d] = mval;
    sS[kl][d] = snapB[(t + kk) * 64 + d];
    __syncthreads();

    // ---- u, o, update (exact round-1/4 code) ----
    const float* uL = wT + 8 * 4096;
    const float* uR = wT + 9 * 4096;
    const float* oL = wT + 10 * 4096;
    const float* oR = wT + 11 * 4096;
    float zU = b_u[d], zO = b_o[d];
#pragma unroll 4
    for (int e = 0; e < 64; e++) {
        float mv = mS[kl][e], sv = sS[kl][e];
        zU = fmaf(mv, uL[e * 64 + d], zU);
        zU = fmaf(sv, uR[e * 64 + d], zU);
        zO = fmaf(mv, oL[e * 64 + d], zO);
        zO = fmaf(sv, oR[e * 64 + d], zO);
    }
    float u  = 1.0f / (1.0f + expf(-zU));
    float o  = fmaxf(zO, 0.0f);
    float mm = mS[kl][d];
    float sv = sS[kl][d];
    float upd = u * o + (1.0f - u) * mm - sv;

    float* Hb = H + b * NNODES * D;
    if (valid) {
        Hb[(i + k) * D + d] += upd;
        if (storeUpd) updWS[b * 2048 + k * 64 + d] = upd;
    }
    // replicate reference quirk: seg-2 of each prop re-applies seg-1's update
    if (reapply && blockIdx.x == 0) {
#pragma unroll
        for (int r = 0; r < 8; r++) {
            int idx = threadIdx.x + 256 * r;  // 2048 = 32 nodes * 64
            Hb[(prev_i + (idx >> 6)) * D + (idx & 63)] += updWS[b * 2048 + idx];
        }
    }
}

extern "C" void kernel_launch(void* const* d_in, const int* in_sizes, int n_in,
                              void* d_out, int out_size, void* d_ws, size_t ws_size,
                              hipStream_t stream) {
    const float* x    = (const float*)d_in[0];
    const float* w_ta = (const float*)d_in[2];
    const float* b_ta = (const float*)d_in[3];
    const float* w_ca = (const float*)d_in[4];
    const float* b_ca = (const float*)d_in[5];
    const float* w_tb = (const float*)d_in[6];
    const float* b_tb = (const float*)d_in[7];
    const float* w_cb = (const float*)d_in[8];
    const float* b_cb = (const float*)d_in[9];
    const float* w_mix= (const float*)d_in[10];
    const float* w_u  = (const float*)d_in[11];
    const float* b_u  = (const float*)d_in[12];
    const float* w_o  = (const float*)d_in[13];
    const float* b_o  = (const float*)d_in[14];

    float* H  = (float*)d_out;           // evolving state, [2][545][64]
    float* ws = (float*)d_ws;
    float* wT    = ws;                   // 12*4096 = 49152
    float* snap  = wT + 49152;           // 2*544*64 = 69632
    float* Pb    = snap + 69632;         // 69632
    float* stT   = Pb + 69632;           // 2*3*128*64 = 49152
    float* stC   = stT + 49152;          // 49152
    float* upd   = stC + 49152;          // 2*2048 = 4096
    float* stFin = upd + 4096;           // 2*2*3*64 = 768   (total ~1.167MB)

    {
        int total = 2 * NNODES * D + 12 * 4096;
        k_init<<<dim3((total + 255) / 256), 256, 0, stream>>>(
            x, w_ta, w_ca, w_tb, w_cb, w_u, w_o, H, wT);
    }

    struct St { int off, t, c, store, reapply, prev_i; };
    const St steps[4] = {
        {0,   1,  32, 1, 0, 0},
        {1,  32, 512, 0, 1, 1},
        {0, 512,  32, 1, 0, 0},
        {512, 32,  1, 0, 1, 512},
    };
    for (int p = 0; p < 2; p++) {
        for (int s = 0; s < 4; s++) {
            St st = steps[s];
            int tilesT = (st.t + 3) / 4, tilesC = (st.c + 3) / 4;
            k_stage<<<dim3(tilesT + tilesC, 2), 256, 0, stream>>>(
                H, wT, snap, Pb, stT, stC, st.off, st.t, st.c);
            k_merge<<<dim3(2, 2), 64, 0, stream>>>(
                stT, stC, stFin, st.t, st.c);
            k_gate<<<dim3((st.c + 3) / 4, 2), 256, 0, stream>>>(
                H, wT, snap, Pb, stFin,
                b_ta, b_ca, b_tb, b_cb, w_mix, b_u, b_o, upd,
                st.off, st.t, st.c, st.store, st.reapply, st.prev_i);
        }
    }
}